// Round 9
// baseline (827.521 us; speedup 1.0000x reference)
//
#include <hip/hip_runtime.h>
#include <math.h>

#define NB   8
#define NPTS 4096
#define MPER 1024
#define MTOT (NB*MPER)
#define CIN  64
#define KNN  64
#define CAP  512
// (0.2*0.2) computed in double, as the reference's python-float R*R
#define R2D  0.04000000000000001

typedef unsigned int u32;
typedef unsigned long long u64;
typedef float v2f __attribute__((ext_vector_type(2)));
using s16x8 = __attribute__((ext_vector_type(8))) short;   // 8 bf16 (4 VGPRs)
using f32x4 = __attribute__((ext_vector_type(4))) float;

// exact IEEE fp32 distance, reference order: ((dx*dx + dy*dy) + dz*dz), no FMA
__device__ __forceinline__ float d2f(float ax, float ay, float az,
                                     float bx, float by, float bz) {
    float dx = __fsub_rn(ax, bx);
    float dy = __fsub_rn(ay, by);
    float dz = __fsub_rn(az, bz);
    return __fadd_rn(__fadd_rn(__fmul_rn(dx, dx), __fmul_rn(dy, dy)),
                     __fmul_rn(dz, dz));
}

// CDNA packed 2xFP32 ops — IEEE-identical per component; asm, never contracted.
// (bit-exactness HW-verified rounds 3/5/6/7: FPS picks matched reference)
__device__ __forceinline__ v2f pk_add(v2f a, v2f b) {
    v2f d;
    asm("v_pk_add_f32 %0, %1, %2" : "=v"(d) : "v"(a), "v"(b));
    return d;
}
__device__ __forceinline__ v2f pk_mul(v2f a, v2f b) {
    v2f d;
    asm("v_pk_mul_f32 %0, %1, %2" : "=v"(d) : "v"(a), "v"(b));
    return d;
}

// float -> bf16 bits, round-to-nearest-even (finite inputs only)
__device__ __forceinline__ unsigned short f2bf(float f) {
    u32 x = __float_as_uint(f);
    u32 r = (x + 0x7fffu + ((x >> 16) & 1u)) >> 16;
    return (unsigned short)r;
}
__device__ __forceinline__ u32 pk2(float a, float b) {
    return (u32)f2bf(a) | ((u32)f2bf(b) << 16);
}

__device__ __forceinline__ f32x4 mfma16(s16x8 a, s16x8 b, f32x4 c) {
    return __builtin_amdgcn_mfma_f32_16x16x32_bf16(a, b, c, 0, 0, 0);
}

// full-wave (64-lane) max reduction of a u64 key via DPP; result valid in lane 63.
__device__ __forceinline__ u64 wave_max_u64_dpp(u64 key)
{
#define DPPMAX(ctrl, rmask) do {                                                   \
        u32 lo_ = (u32)key;                                                        \
        u32 hi_ = (u32)(key >> 32);                                                \
        u32 plo = (u32)__builtin_amdgcn_update_dpp(                                \
            0, (int)lo_, ctrl, rmask, 0xf, false);                                 \
        u32 phi = (u32)__builtin_amdgcn_update_dpp(                                \
            0, (int)hi_, ctrl, rmask, 0xf, false);                                 \
        u64 pk = ((u64)phi << 32) | plo;                                           \
        if (pk > key) key = pk;                                                    \
    } while (0)
    DPPMAX(0x111, 0xf);   // row_shr:1
    DPPMAX(0x112, 0xf);   // row_shr:2
    DPPMAX(0x114, 0xf);   // row_shr:4
    DPPMAX(0x118, 0xf);   // row_shr:8
    DPPMAX(0x142, 0xa);   // row_bcast:15 -> rows 1,3
    DPPMAX(0x143, 0xc);   // row_bcast:31 -> rows 2,3
#undef DPPMAX
    return key;
}

// ---------------- Kernel 1: farthest point sampling ----------------
// round-7 structure, ONE delta: 512 threads (8 waves = 2 waves/SIMD) so each
// SIMD has a co-resident wave to hide the dependent-chain latency (argmax
// chain, DPP chain, tail LDS reads). 8 pts/thread (4 pk pairs). Direct
// in-loop global sel store (round-7 proven; round-8 LDS buffering regressed).
__global__ __launch_bounds__(512) void fps_kernel(const float* __restrict__ pos,
                                                  int* __restrict__ sel)
{
    const int b    = blockIdx.x;
    const int t    = threadIdx.x;
    const int lane = t & 63;
    const int wv   = t >> 6;             // 0..7
    const float* pb = pos + (size_t)b * NPTS * 3;

    __shared__ float4 lp[NPTS];          // interleaved coords (64 KB)
    __shared__ u64 part[2][8];

    v2f px[4], py[4], pz[4], mind[4];
#pragma unroll
    for (int pr = 0; pr < 4; ++pr) {
        int j0 = (2 * pr + 0) * 512 + t;
        int j1 = (2 * pr + 1) * 512 + t;
        float x0 = pb[j0 * 3 + 0], y0 = pb[j0 * 3 + 1], z0 = pb[j0 * 3 + 2];
        float x1 = pb[j1 * 3 + 0], y1 = pb[j1 * 3 + 1], z1 = pb[j1 * 3 + 2];
        px[pr] = v2f{x0, x1}; py[pr] = v2f{y0, y1}; pz[pr] = v2f{z0, z1};
        mind[pr] = v2f{3.0e38f, 3.0e38f};   // first fmin yields exactly d2-to-p0
        lp[j0] = float4{x0, y0, z0, 0.f};
        lp[j1] = float4{x1, y1, z1, 0.f};
    }
    if (t == 0) sel[b * MPER + 0] = b * NPTS + 0;
    __syncthreads();

    float4 c0 = lp[0];
    float cx = c0.x, cy = c0.y, cz = c0.z;

    for (int it = 1; it < MPER; ++it) {
        const v2f ncx = v2f{-cx, -cx};
        const v2f ncy = v2f{-cy, -cy};
        const v2f ncz = v2f{-cz, -cz};

        // local argmax of updated min-dists (ascending j + strict > keeps the
        // lowest index on ties, matching jnp.argmax)
        float bv = -1.0f; int bi = 0;
#pragma unroll
        for (int pr = 0; pr < 4; ++pr) {
            v2f dx = pk_add(px[pr], ncx);          // p + (-c) == p - c exactly
            v2f dy = pk_add(py[pr], ncy);
            v2f dz = pk_add(pz[pr], ncz);
            v2f s  = pk_add(pk_mul(dx, dx), pk_mul(dy, dy));
            v2f d2 = pk_add(s, pk_mul(dz, dz));    // ((dx^2+dy^2)+dz^2), exact order
            float m0 = fminf(mind[pr].x, d2.x);
            float m1 = fminf(mind[pr].y, d2.y);
            mind[pr].x = m0; mind[pr].y = m1;
            if (m0 > bv) { bv = m0; bi = (2 * pr + 0) * 512 + t; }
            if (m1 > bv) { bv = m1; bi = (2 * pr + 1) * 512 + t; }
        }

        // pack (d2 bits, ~idx): max key == (max d2, then min idx). d2 >= 0 so
        // float bits are order-isomorphic.
        u64 key = ((u64)__float_as_uint(bv) << 32) | (u32)(~bi);
        key = wave_max_u64_dpp(key);

        const int p = it & 1;
        if (lane == 63) part[p][wv] = key;
        __syncthreads();

        u64 k0 = part[p][0], k1 = part[p][1], k2 = part[p][2], k3 = part[p][3];
        u64 k4 = part[p][4], k5 = part[p][5], k6 = part[p][6], k7 = part[p][7];
        u64 ka = k0 > k1 ? k0 : k1;
        u64 kb = k2 > k3 ? k2 : k3;
        u64 kc = k4 > k5 ? k4 : k5;
        u64 kd = k6 > k7 ? k6 : k7;
        u64 ke = ka > kb ? ka : kb;
        u64 kf = kc > kd ? kc : kd;
        u64 km = ke > kf ? ke : kf;
        int pick = (int)(~(u32)km);

        float4 cc = lp[pick];            // single b128 broadcast
        cx = cc.x; cy = cc.y; cz = cc.z;
        if (t == 0) sel[b * MPER + it] = b * NPTS + pick;   // overlaps phase A
    }
}

// ---------------- Kernel 2: ball query + K nearest (rank select) ----------------
__global__ __launch_bounds__(256) void ballq_kernel(
    const float* __restrict__ pos, const int* __restrict__ sel,
    int* __restrict__ nbr, int* __restrict__ cnt,
    float* __restrict__ out_pos, float* __restrict__ out_batch)
{
    __shared__ float cd[4][CAP];
    __shared__ int   ci[4][CAP];

    const int wv   = threadIdx.x >> 6;
    const int lane = threadIdx.x & 63;
    const int c    = blockIdx.x * 4 + wv;
    const int sg   = sel[c];
    const int b    = c >> 10;            // c / MPER
    const int base = b * NPTS;
    const float* pb = pos + (size_t)base * 3;
    const float qx = pos[(size_t)sg * 3 + 0];
    const float qy = pos[(size_t)sg * 3 + 1];
    const float qz = pos[(size_t)sg * 3 + 2];

    int n = 0;
    for (int r0 = 0; r0 < NPTS; r0 += 64) {
        const int j = r0 + lane;
        float x = pb[j * 3 + 0], y = pb[j * 3 + 1], z = pb[j * 3 + 2];
        float d2 = d2f(x, y, z, qx, qy, qz);
        bool inside = ((double)d2 <= R2D);
        unsigned long long m = __ballot(inside);
        if (inside) {
            int myoff = n + __popcll(m & ((1ull << lane) - 1ull));
            if (myoff < CAP) { cd[wv][myoff] = d2; ci[wv][myoff] = j; }
        }
        n += __popcll(m);
    }
    n = min(n, CAP);
    __syncthreads();

    for (int i = lane; i < n; i += 64) {
        float d = cd[wv][i]; int id = ci[wv][i];
        int rank = 0;
        for (int j = 0; j < n; ++j) {
            float dj = cd[wv][j]; int ij = ci[wv][j];
            rank += (dj < d || (dj == d && ij < id)) ? 1 : 0;
        }
        if (rank < KNN) nbr[(size_t)c * KNN + rank] = base + id;
    }
    if (lane == 0) {
        cnt[c] = min(n, KNN);
        out_pos[c * 3 + 0] = qx;
        out_pos[c * 3 + 1] = qy;
        out_pos[c * 3 + 2] = qz;
        out_batch[c] = (float)b;
    }
}

// ---------------- weight prep: bf16 transposed+padded weights into ws ----------
// ws layout (ushort units): W1t[64][104] | W2t[64][72] | W3t[128][72]
#define W1T_U 6656
#define W2T_U 4608
#define W3T_U 9216
#define WTOT_U 20480

__global__ __launch_bounds__(256) void prep_weights(
    const float* __restrict__ W1, const float* __restrict__ W2,
    const float* __restrict__ W3, unsigned short* __restrict__ wsW)
{
    int i = blockIdx.x * 256 + threadIdx.x;
    if (i >= WTOT_U) return;
    float v;
    if (i < W1T_U) {
        int cr = i / 104, k = i - cr * 104;
        v = (k < 67) ? W1[k * 64 + cr] : 0.0f;
    } else if (i < W1T_U + W2T_U) {
        int j = i - W1T_U;
        int cr = j / 72, k = j - cr * 72;
        v = (k < 64) ? W2[k * 64 + cr] : 0.0f;
    } else {
        int j = i - (W1T_U + W2T_U);
        int cr = j / 72, k = j - cr * 72;
        v = (k < 64) ? W3[k * 128 + cr] : 0.0f;
    }
    wsW[i] = f2bf(v);
}

// ---------------- Kernel 3: gather + MFMA MLP + masked max ---------------------
__global__ __launch_bounds__(256) void mlp_kernel(
    const float* __restrict__ x, const float* __restrict__ pos,
    const int* __restrict__ nbr, const int* __restrict__ cnt,
    const float* __restrict__ out_pos,
    const unsigned short* __restrict__ wsW,
    const float* __restrict__ b1, const float* __restrict__ b2,
    const float* __restrict__ b3,
    float* __restrict__ out_x)
{
    __shared__ __align__(16) unsigned short smA[6656];   // A1[64][104]; later H2[64][72]; later f32 partial[4][128]
    __shared__ __align__(16) unsigned short smW[WTOT_U]; // W1t (later H1[64][72]) | W2t | W3t

    const int c = blockIdx.x;
    const int t = threadIdx.x;
    const int n = cnt[c];

    // ---- stage weights ws -> LDS (linear, 40960 B) ----
    {
        const uint4* src = (const uint4*)wsW;
        uint4* dst = (uint4*)smW;
#pragma unroll
        for (int i = 0; i < 10; ++i) dst[t + 256 * i] = src[t + 256 * i];
    }

    // ---- stage A1: row k = [bf16(x[nb][0..64)), bf16(pos[nb]-q), zeros] ----
    {
        const int k = t >> 2, g = t & 3;
        const bool valid = k < n;
        const int nb = valid ? nbr[(size_t)c * KNN + k] : 0;
        const float* xr = x + (size_t)nb * CIN + g * 16;
        float4 f0, f1, f2, f3;
        if (valid) {
            f0 = *(const float4*)(xr + 0);
            f1 = *(const float4*)(xr + 4);
            f2 = *(const float4*)(xr + 8);
            f3 = *(const float4*)(xr + 12);
        } else {
            f0 = float4{0.f, 0.f, 0.f, 0.f};
            f1 = f0; f2 = f0; f3 = f0;
        }
        uint4 ua = { pk2(f0.x, f0.y), pk2(f0.z, f0.w), pk2(f1.x, f1.y), pk2(f1.z, f1.w) };
        uint4 ub = { pk2(f2.x, f2.y), pk2(f2.z, f2.w), pk2(f3.x, f3.y), pk2(f3.z, f3.w) };
        *(uint4*)&smA[k * 104 + g * 16 + 0] = ua;
        *(uint4*)&smA[k * 104 + g * 16 + 8] = ub;
        if (g == 0) {
            float r0 = 0.f, r1 = 0.f, r2 = 0.f;
            if (valid) {
                float q0 = out_pos[c * 3 + 0];
                float q1 = out_pos[c * 3 + 1];
                float q2 = out_pos[c * 3 + 2];
                r0 = __fsub_rn(pos[(size_t)nb * 3 + 0], q0);
                r1 = __fsub_rn(pos[(size_t)nb * 3 + 1], q1);
                r2 = __fsub_rn(pos[(size_t)nb * 3 + 2], q2);
            }
            uint4 uz = { 0u, 0u, 0u, 0u };
            uint4 ur = { pk2(r0, r1), (u32)f2bf(r2), 0u, 0u };
            *(uint4*)&smA[k * 104 + 64] = ur;
            *(uint4*)&smA[k * 104 + 72] = uz;
            *(uint4*)&smA[k * 104 + 80] = uz;
            *(uint4*)&smA[k * 104 + 88] = uz;
            *(uint4*)&smA[k * 104 + 96] = uz;
        }
    }
    __syncthreads();

    const int l  = t & 63;
    const int w  = t >> 6;
    const int lr = l & 15;
    const int kg = l >> 4;

    float bias1[4], bias2[4];
#pragma unroll
    for (int nt = 0; nt < 4; ++nt) {
        bias1[nt] = b1[nt * 16 + lr];
        bias2[nt] = b2[nt * 16 + lr];
    }

    const unsigned short* W1t = smW;                    // stride 104
    const unsigned short* W2t = smW + W1T_U;            // stride 72
    const unsigned short* W3t = smW + W1T_U + W2T_U;    // stride 72
    unsigned short* H1 = smW;                           // [64][72] overlays W1t
    unsigned short* H2 = smA;                           // [64][72] overlays A1

    // ---- layer 1: A1[64][96+] x W1t -> H1 (relu) ----
    f32x4 acc1[4];
#pragma unroll
    for (int nt = 0; nt < 4; ++nt) acc1[nt] = f32x4{0.f, 0.f, 0.f, 0.f};
    {
        const int ao = (w * 16 + lr) * 104 + kg * 8;
        const int bo = lr * 104 + kg * 8;
#pragma unroll
        for (int kc = 0; kc < 3; ++kc) {
            s16x8 af = *(const s16x8*)&smA[ao + kc * 32];
#pragma unroll
            for (int nt = 0; nt < 4; ++nt) {
                s16x8 bf = *(const s16x8*)&W1t[bo + nt * 1664 + kc * 32];
                acc1[nt] = mfma16(af, bf, acc1[nt]);
            }
        }
    }
    __syncthreads();   // all W1t/A1 reads complete before overlaying W1t with H1
#pragma unroll
    for (int nt = 0; nt < 4; ++nt) {
        const int col = nt * 16 + lr;
#pragma unroll
        for (int r = 0; r < 4; ++r) {
            const int row = w * 16 + kg * 4 + r;
            float v = fmaxf(acc1[nt][r] + bias1[nt], 0.0f);
            H1[row * 72 + col] = f2bf(v);
        }
    }
    __syncthreads();

    // ---- layer 2: H1 x W2t -> H2 (relu) ----
    f32x4 acc2[4];
#pragma unroll
    for (int nt = 0; nt < 4; ++nt) acc2[nt] = f32x4{0.f, 0.f, 0.f, 0.f};
    {
        const int ao = (w * 16 + lr) * 72 + kg * 8;
        const int bo = lr * 72 + kg * 8;
#pragma unroll
        for (int kc = 0; kc < 2; ++kc) {
            s16x8 af = *(const s16x8*)&H1[ao + kc * 32];
#pragma unroll
            for (int nt = 0; nt < 4; ++nt) {
                s16x8 bf = *(const s16x8*)&W2t[bo + nt * 1152 + kc * 32];
                acc2[nt] = mfma16(af, bf, acc2[nt]);
            }
        }
    }
    // H2 overlays A1 (dead since layer-1 barrier); disjoint from H1/W2t.
#pragma unroll
    for (int nt = 0; nt < 4; ++nt) {
        const int col = nt * 16 + lr;
#pragma unroll
        for (int r = 0; r < 4; ++r) {
            const int row = w * 16 + kg * 4 + r;
            float v = fmaxf(acc2[nt][r] + bias2[nt], 0.0f);
            H2[row * 72 + col] = f2bf(v);
        }
    }
    __syncthreads();

    // ---- layer 3: H2 x W3t -> acc3 (64x128 per block) ----
    f32x4 acc3[8];
#pragma unroll
    for (int nt = 0; nt < 8; ++nt) acc3[nt] = f32x4{0.f, 0.f, 0.f, 0.f};
    {
        const int ao = (w * 16 + lr) * 72 + kg * 8;
        const int bo = lr * 72 + kg * 8;
#pragma unroll
        for (int kc = 0; kc < 2; ++kc) {
            s16x8 af = *(const s16x8*)&H2[ao + kc * 32];
#pragma unroll
            for (int nt = 0; nt < 8; ++nt) {
                s16x8 bf = *(const s16x8*)&W3t[bo + nt * 1152 + kc * 32];
                acc3[nt] = mfma16(af, bf, acc3[nt]);
            }
        }
    }

    // ---- masked max over valid rows; bias added after max (column-constant) ----
    float pm[8];
#pragma unroll
    for (int nt = 0; nt < 8; ++nt) pm[nt] = -1e30f;
#pragma unroll
    for (int r = 0; r < 4; ++r) {
        const int row = w * 16 + kg * 4 + r;
        if (row < n) {
#pragma unroll
            for (int nt = 0; nt < 8; ++nt) pm[nt] = fmaxf(pm[nt], acc3[nt][r]);
        }
    }
#pragma unroll
    for (int nt = 0; nt < 8; ++nt) {
        pm[nt] = fmaxf(pm[nt], __shfl_xor(pm[nt], 16));
        pm[nt] = fmaxf(pm[nt], __shfl_xor(pm[nt], 32));
    }
    __syncthreads();   // all layer-3 LDS reads done; reuse smA as f32 partials
    float* pbuf = (float*)smA;            // [4][128]
    if (kg == 0) {
#pragma unroll
        for (int nt = 0; nt < 8; ++nt) pbuf[w * 128 + nt * 16 + lr] = pm[nt];
    }
    __syncthreads();
    if (t < 128) {
        float m = fmaxf(fmaxf(pbuf[t], pbuf[128 + t]),
                        fmaxf(pbuf[256 + t], pbuf[384 + t]));
        out_x[(size_t)c * 128 + t] = m + b3[t];
    }
}

extern "C" void kernel_launch(void* const* d_in, const int* in_sizes, int n_in,
                              void* d_out, int out_size, void* d_ws, size_t ws_size,
                              hipStream_t stream)
{
    const float* x   = (const float*)d_in[0];
    const float* pos = (const float*)d_in[1];
    const float* W1 = (const float*)d_in[3];
    const float* b1 = (const float*)d_in[4];
    const float* W2 = (const float*)d_in[5];
    const float* b2 = (const float*)d_in[6];
    const float* W3 = (const float*)d_in[7];
    const float* b3 = (const float*)d_in[8];

    float* out_x     = (float*)d_out;                    // [8192,128]
    float* out_pos   = out_x + (size_t)MTOT * 128;       // [8192,3]
    float* out_batch = out_pos + (size_t)MTOT * 3;       // [8192]

    int* sel = (int*)d_ws;                               // [8192]
    int* nbr = sel + MTOT;                               // [8192*64]
    int* cnt = nbr + (size_t)MTOT * KNN;                 // [8192]
    unsigned short* wsW = (unsigned short*)(cnt + MTOT); // [20480] bf16 weights

    prep_weights<<<(WTOT_U + 255) / 256, 256, 0, stream>>>(W1, W2, W3, wsW);
    fps_kernel<<<NB, 512, 0, stream>>>(pos, sel);
    ballq_kernel<<<MTOT / 4, 256, 0, stream>>>(pos, sel, nbr, cnt, out_pos, out_batch);
    mlp_kernel<<<MTOT, 256, 0, stream>>>(x, pos, nbr, cnt, out_pos, wsW,
                                         b1, b2, b3, out_x);
}

// Round 10
// 713.326 us; speedup vs baseline: 1.1601x; 1.1601x over previous
//
#include <hip/hip_runtime.h>
#include <math.h>

#define NB   8
#define NPTS 4096
#define MPER 1024
#define MTOT (NB*MPER)
#define CIN  64
#define KNN  64
#define PUB  16
// (0.2*0.2) computed in double, as the reference's python-float R*R
#define R2D  0.04000000000000001

typedef unsigned int u32;
typedef unsigned long long u64;
typedef float v2f __attribute__((ext_vector_type(2)));
using s16x8 = __attribute__((ext_vector_type(8))) short;   // 8 bf16 (4 VGPRs)
using f32x4 = __attribute__((ext_vector_type(4))) float;

// exact IEEE fp32 distance, reference order: ((dx*dx + dy*dy) + dz*dz), no FMA
__device__ __forceinline__ float d2f(float ax, float ay, float az,
                                     float bx, float by, float bz) {
    float dx = __fsub_rn(ax, bx);
    float dy = __fsub_rn(ay, by);
    float dz = __fsub_rn(az, bz);
    return __fadd_rn(__fadd_rn(__fmul_rn(dx, dx), __fmul_rn(dy, dy)),
                     __fmul_rn(dz, dz));
}

// CDNA packed 2xFP32 ops — IEEE-identical per component; asm, never contracted.
__device__ __forceinline__ v2f pk_add(v2f a, v2f b) {
    v2f d;
    asm("v_pk_add_f32 %0, %1, %2" : "=v"(d) : "v"(a), "v"(b));
    return d;
}
__device__ __forceinline__ v2f pk_mul(v2f a, v2f b) {
    v2f d;
    asm("v_pk_mul_f32 %0, %1, %2" : "=v"(d) : "v"(a), "v"(b));
    return d;
}

// float -> bf16 bits, round-to-nearest-even (finite inputs only)
__device__ __forceinline__ unsigned short f2bf(float f) {
    u32 x = __float_as_uint(f);
    u32 r = (x + 0x7fffu + ((x >> 16) & 1u)) >> 16;
    return (unsigned short)r;
}
__device__ __forceinline__ u32 pk2(float a, float b) {
    return (u32)f2bf(a) | ((u32)f2bf(b) << 16);
}

__device__ __forceinline__ f32x4 mfma16(s16x8 a, s16x8 b, f32x4 c) {
    return __builtin_amdgcn_mfma_f32_16x16x32_bf16(a, b, c, 0, 0, 0);
}

// full-wave (64-lane) max reduction of a u64 key via DPP; result valid in lane 63.
__device__ __forceinline__ u64 wave_max_u64_dpp(u64 key)
{
#define DPPMAX(ctrl, rmask) do {                                                   \
        u32 lo_ = (u32)key;                                                        \
        u32 hi_ = (u32)(key >> 32);                                                \
        u32 plo = (u32)__builtin_amdgcn_update_dpp(                                \
            0, (int)lo_, ctrl, rmask, 0xf, false);                                 \
        u32 phi = (u32)__builtin_amdgcn_update_dpp(                                \
            0, (int)hi_, ctrl, rmask, 0xf, false);                                 \
        u64 pk = ((u64)phi << 32) | plo;                                           \
        if (pk > key) key = pk;                                                    \
    } while (0)
    DPPMAX(0x111, 0xf);   // row_shr:1
    DPPMAX(0x112, 0xf);   // row_shr:2
    DPPMAX(0x114, 0xf);   // row_shr:4
    DPPMAX(0x118, 0xf);   // row_shr:8
    DPPMAX(0x142, 0xa);   // row_bcast:15 -> rows 1,3
    DPPMAX(0x143, 0xc);   // row_bcast:31 -> rows 2,3
#undef DPPMAX
    return key;
}

// ---------------- weight prep: bf16 transposed+padded weights into ws ----------
#define W1T_U 6656
#define W2T_U 4608
#define W3T_U 9216
#define WTOT_U 20480

__global__ __launch_bounds__(256) void prep_weights(
    const float* __restrict__ W1, const float* __restrict__ W2,
    const float* __restrict__ W3, unsigned short* __restrict__ wsW)
{
    int i = blockIdx.x * 256 + threadIdx.x;
    if (i >= WTOT_U) return;
    float v;
    if (i < W1T_U) {
        int cr = i / 104, k = i - cr * 104;
        v = (k < 67) ? W1[k * 64 + cr] : 0.0f;
    } else if (i < W1T_U + W2T_U) {
        int j = i - W1T_U;
        int cr = j / 72, k = j - cr * 72;
        v = (k < 64) ? W2[k * 64 + cr] : 0.0f;
    } else {
        int j = i - (W1T_U + W2T_U);
        int cr = j / 72, k = j - cr * 72;
        v = (k < 64) ? W3[k * 128 + cr] : 0.0f;
    }
    wsW[i] = f2bf(v);
}

// ---------------- sync init: reset progress + work queue each call -------------
__global__ __launch_bounds__(64) void init_sync(int* __restrict__ prog,
                                                int* __restrict__ wq)
{
    int t = threadIdx.x;
    if (t < NB) prog[t * 16] = -1;
    if (t == NB) *wq = 0;
}

// ================= fused kernel: 8 FPS blocks + 248 persistent workers =========
// dynamic LDS = 86016 B -> exactly 1 block/CU (2x86016 > 160KB), so all 256
// blocks of the grid are co-resident (256 CUs) and workers never share a CU
// with an FPS block. FPS publishes sel[] (agent atomics) + prog[b] (release,
// every PUB iters); workers pull slots from a global queue in publish order.

// ---- FPS producer (r7-proven structure; 591us standalone) ----
__device__ __forceinline__ void fps_body(char* smem, const float* __restrict__ pos,
                                         int* __restrict__ sel, int* __restrict__ prog)
{
    const int b    = blockIdx.x;
    const int t    = threadIdx.x;
    const int lane = t & 63;
    const int wv   = t >> 6;
    const float* pb = pos + (size_t)b * NPTS * 3;

    float4* lp = (float4*)smem;              // 64 KB
    u64*    part = (u64*)(smem + 65536);     // [2][4]

    v2f px[8], py[8], pz[8], mind[8];
#pragma unroll
    for (int pr = 0; pr < 8; ++pr) {
        int j0 = (2 * pr + 0) * 256 + t;
        int j1 = (2 * pr + 1) * 256 + t;
        float x0 = pb[j0 * 3 + 0], y0 = pb[j0 * 3 + 1], z0 = pb[j0 * 3 + 2];
        float x1 = pb[j1 * 3 + 0], y1 = pb[j1 * 3 + 1], z1 = pb[j1 * 3 + 2];
        px[pr] = v2f{x0, x1}; py[pr] = v2f{y0, y1}; pz[pr] = v2f{z0, z1};
        mind[pr] = v2f{3.0e38f, 3.0e38f};
        lp[j0] = float4{x0, y0, z0, 0.f};
        lp[j1] = float4{x1, y1, z1, 0.f};
    }
    if (t == 0)
        __hip_atomic_store(&sel[b * MPER + 0], b * NPTS + 0,
                           __ATOMIC_RELAXED, __HIP_MEMORY_SCOPE_AGENT);
    __syncthreads();

    float4 c0 = lp[0];
    float cx = c0.x, cy = c0.y, cz = c0.z;

    for (int it = 1; it < MPER; ++it) {
        const v2f ncx = v2f{-cx, -cx};
        const v2f ncy = v2f{-cy, -cy};
        const v2f ncz = v2f{-cz, -cz};

        float bv = -1.0f; int bi = 0;
#pragma unroll
        for (int pr = 0; pr < 8; ++pr) {
            v2f dx = pk_add(px[pr], ncx);
            v2f dy = pk_add(py[pr], ncy);
            v2f dz = pk_add(pz[pr], ncz);
            v2f s  = pk_add(pk_mul(dx, dx), pk_mul(dy, dy));
            v2f d2 = pk_add(s, pk_mul(dz, dz));
            float m0 = fminf(mind[pr].x, d2.x);
            float m1 = fminf(mind[pr].y, d2.y);
            mind[pr].x = m0; mind[pr].y = m1;
            if (m0 > bv) { bv = m0; bi = (2 * pr + 0) * 256 + t; }
            if (m1 > bv) { bv = m1; bi = (2 * pr + 1) * 256 + t; }
        }

        u64 key = ((u64)__float_as_uint(bv) << 32) | (u32)(~bi);
        key = wave_max_u64_dpp(key);

        const int p = it & 1;
        if (lane == 63) part[p * 4 + wv] = key;
        __syncthreads();

        u64 k0 = part[p * 4 + 0];
        u64 k1 = part[p * 4 + 1];
        u64 k2 = part[p * 4 + 2];
        u64 k3 = part[p * 4 + 3];
        u64 ka = k0 > k1 ? k0 : k1;
        u64 kb = k2 > k3 ? k2 : k3;
        u64 km = ka > kb ? ka : kb;
        int pick = (int)(~(u32)km);

        float4 cc = lp[pick];
        cx = cc.x; cy = cc.y; cz = cc.z;
        if (t == 0) {
            __hip_atomic_store(&sel[b * MPER + it], b * NPTS + pick,
                               __ATOMIC_RELAXED, __HIP_MEMORY_SCOPE_AGENT);
            if ((it & (PUB - 1)) == (PUB - 1))
                __hip_atomic_store(&prog[b * 16], it,
                                   __ATOMIC_RELEASE, __HIP_MEMORY_SCOPE_AGENT);
        }
    }
}

// ---- worker: queue -> wait publish -> ballq -> MFMA MLP -> outputs ----
__device__ __forceinline__ void worker_loop(
    char* smem, const float* __restrict__ pos, const float* __restrict__ x,
    const unsigned short* __restrict__ wsW,
    const float* __restrict__ b1, const float* __restrict__ b2,
    const float* __restrict__ b3,
    int* __restrict__ sel, int* __restrict__ prog, int* __restrict__ wq,
    float* __restrict__ out_x, float* __restrict__ out_pos,
    float* __restrict__ out_batch)
{
    const int t = threadIdx.x;
    const int l = t & 63, w = t >> 6, lr = l & 15, kg = l >> 4;

    unsigned short* sW   = (unsigned short*)smem;              // 40960 B
    unsigned short* sA1  = (unsigned short*)(smem + 40960);    // [64][104]
    unsigned short* sH1  = (unsigned short*)(smem + 54272);    // [64][72]
    unsigned short* sH2  = (unsigned short*)(smem + 63488);    // [64][72]
    float* cd   = (float*)(smem + 72704);                      // [4][128]
    int*   ci   = (int*)(smem + 74752);                        // [4][128]
    int*   nbrl = (int*)(smem + 76800);                        // [64]
    int*   scnt = (int*)(smem + 77056);                        // [4]
    float* sq   = (float*)(smem + 77072);                      // [3]
    int*   sslot= (int*)(smem + 77084);                        // [1]

    // stage weights once (persist across centroids)
    {
        const uint4* src = (const uint4*)wsW;
        uint4* dst = (uint4*)sW;
#pragma unroll
        for (int i = 0; i < 10; ++i) dst[t + 256 * i] = src[t + 256 * i];
    }
    float bias1[4], bias2[4];
#pragma unroll
    for (int nt = 0; nt < 4; ++nt) {
        bias1[nt] = b1[nt * 16 + lr];
        bias2[nt] = b2[nt * 16 + lr];
    }
    const float b3r = (t < 128) ? b3[t] : 0.0f;

    const unsigned short* W1t = sW;                 // stride 104
    const unsigned short* W2t = sW + W1T_U;         // stride 72
    const unsigned short* W3t = sW + W1T_U + W2T_U; // stride 72

    for (;;) {
        if (t == 0) {
            int s = __hip_atomic_fetch_add(wq, 1, __ATOMIC_RELAXED,
                                           __HIP_MEMORY_SCOPE_AGENT);
            sslot[0] = s;
            if (s < MTOT) {
                const int it = s >> 3, b = s & 7;
                const int c = b * MPER + it;
                int p_;
                do {
                    p_ = __hip_atomic_load(&prog[b * 16], __ATOMIC_ACQUIRE,
                                           __HIP_MEMORY_SCOPE_AGENT);
                    if (p_ < it) __builtin_amdgcn_s_sleep(32);
                } while (p_ < it);
                int sg = __hip_atomic_load(&sel[c], __ATOMIC_RELAXED,
                                           __HIP_MEMORY_SCOPE_AGENT);
                float qx = pos[(size_t)sg * 3 + 0];
                float qy = pos[(size_t)sg * 3 + 1];
                float qz = pos[(size_t)sg * 3 + 2];
                sq[0] = qx; sq[1] = qy; sq[2] = qz;
                out_pos[(size_t)c * 3 + 0] = qx;
                out_pos[(size_t)c * 3 + 1] = qy;
                out_pos[(size_t)c * 3 + 2] = qz;
                out_batch[c] = (float)b;
            }
        }
        __syncthreads();
        const int s = sslot[0];
        if (s >= MTOT) break;                        // block-uniform exit
        const int it = s >> 3, b = s & 7;
        const int c = b * MPER + it;
        const float qx = sq[0], qy = sq[1], qz = sq[2];

        // ---- ballq: wave w scans quarter [w*1024,(w+1)*1024); rank select is
        // order-independent, so the 4-way segmented compaction preserves output
        const float* pb2 = pos + (size_t)b * NPTS * 3;
        int nw = 0;
        for (int r0 = 0; r0 < 1024; r0 += 64) {
            int j = w * 1024 + r0 + l;
            float xx = pb2[j * 3 + 0], yy = pb2[j * 3 + 1], zz = pb2[j * 3 + 2];
            float d2 = d2f(xx, yy, zz, qx, qy, qz);
            bool inside = ((double)d2 <= R2D);
            u64 m = __ballot(inside);
            if (inside) {
                int off = nw + __popcll(m & ((1ull << l) - 1ull));
                if (off < 128) { cd[w * 128 + off] = d2; ci[w * 128 + off] = j; }
            }
            nw += __popcll(m);
        }
        nw = min(nw, 128);
        if (l == 0) scnt[w] = nw;
        __syncthreads();
        const int n0 = scnt[0], n1 = scnt[1], n2 = scnt[2], n3 = scnt[3];
        const int ntot = n0 + n1 + n2 + n3;
        const int cnt = min(ntot, KNN);

        for (int f = t; f < ntot; f += 256) {
            int w2, i2;
            if (f < n0)                { w2 = 0; i2 = f; }
            else if (f < n0 + n1)      { w2 = 1; i2 = f - n0; }
            else if (f < n0 + n1 + n2) { w2 = 2; i2 = f - n0 - n1; }
            else                       { w2 = 3; i2 = f - n0 - n1 - n2; }
            float d = cd[w2 * 128 + i2]; int id = ci[w2 * 128 + i2];
            int rank = 0;
#pragma unroll
            for (int w3 = 0; w3 < 4; ++w3) {
                int nn = scnt[w3];
                for (int j = 0; j < nn; ++j) {
                    float dj = cd[w3 * 128 + j]; int ij = ci[w3 * 128 + j];
                    rank += (dj < d || (dj == d && ij < id)) ? 1 : 0;
                }
            }
            if (rank < KNN) nbrl[rank] = id;
        }
        __syncthreads();

        // ---- A1 staging: row k = [bf16(x[nb]), bf16(pos[nb]-q), zeros] ----
        {
            const int k = t >> 2, g = t & 3;
            const bool valid = k < cnt;
            const int nbg = valid ? (b * NPTS + nbrl[k]) : 0;
            const float* xr = x + (size_t)nbg * CIN + g * 16;
            float4 f0, f1, f2, f3;
            if (valid) {
                f0 = *(const float4*)(xr + 0);
                f1 = *(const float4*)(xr + 4);
                f2 = *(const float4*)(xr + 8);
                f3 = *(const float4*)(xr + 12);
            } else {
                f0 = float4{0.f, 0.f, 0.f, 0.f};
                f1 = f0; f2 = f0; f3 = f0;
            }
            uint4 ua = { pk2(f0.x, f0.y), pk2(f0.z, f0.w), pk2(f1.x, f1.y), pk2(f1.z, f1.w) };
            uint4 ub = { pk2(f2.x, f2.y), pk2(f2.z, f2.w), pk2(f3.x, f3.y), pk2(f3.z, f3.w) };
            *(uint4*)&sA1[k * 104 + g * 16 + 0] = ua;
            *(uint4*)&sA1[k * 104 + g * 16 + 8] = ub;
            if (g == 0) {
                float r0 = 0.f, r1 = 0.f, r2 = 0.f;
                if (valid) {
                    r0 = __fsub_rn(pos[(size_t)nbg * 3 + 0], qx);
                    r1 = __fsub_rn(pos[(size_t)nbg * 3 + 1], qy);
                    r2 = __fsub_rn(pos[(size_t)nbg * 3 + 2], qz);
                }
                uint4 uz = { 0u, 0u, 0u, 0u };
                uint4 ur = { pk2(r0, r1), (u32)f2bf(r2), 0u, 0u };
                *(uint4*)&sA1[k * 104 + 64] = ur;
                *(uint4*)&sA1[k * 104 + 72] = uz;
                *(uint4*)&sA1[k * 104 + 80] = uz;
                *(uint4*)&sA1[k * 104 + 88] = uz;
                *(uint4*)&sA1[k * 104 + 96] = uz;
            }
        }
        __syncthreads();

        // ---- layer 1: A1 x W1t -> H1 (relu) ----
        f32x4 acc1[4];
#pragma unroll
        for (int nt = 0; nt < 4; ++nt) acc1[nt] = f32x4{0.f, 0.f, 0.f, 0.f};
        {
            const int ao = (w * 16 + lr) * 104 + kg * 8;
            const int bo = lr * 104 + kg * 8;
#pragma unroll
            for (int kc = 0; kc < 3; ++kc) {
                s16x8 af = *(const s16x8*)&sA1[ao + kc * 32];
#pragma unroll
                for (int nt = 0; nt < 4; ++nt) {
                    s16x8 bf = *(const s16x8*)&W1t[bo + nt * 1664 + kc * 32];
                    acc1[nt] = mfma16(af, bf, acc1[nt]);
                }
            }
        }
#pragma unroll
        for (int nt = 0; nt < 4; ++nt) {
            const int col = nt * 16 + lr;
#pragma unroll
            for (int r = 0; r < 4; ++r) {
                const int row = w * 16 + kg * 4 + r;
                float v = fmaxf(acc1[nt][r] + bias1[nt], 0.0f);
                sH1[row * 72 + col] = f2bf(v);
            }
        }
        __syncthreads();

        // ---- layer 2: H1 x W2t -> H2 (relu) ----
        f32x4 acc2[4];
#pragma unroll
        for (int nt = 0; nt < 4; ++nt) acc2[nt] = f32x4{0.f, 0.f, 0.f, 0.f};
        {
            const int ao = (w * 16 + lr) * 72 + kg * 8;
            const int bo = lr * 72 + kg * 8;
#pragma unroll
            for (int kc = 0; kc < 2; ++kc) {
                s16x8 af = *(const s16x8*)&sH1[ao + kc * 32];
#pragma unroll
                for (int nt = 0; nt < 4; ++nt) {
                    s16x8 bf = *(const s16x8*)&W2t[bo + nt * 1152 + kc * 32];
                    acc2[nt] = mfma16(af, bf, acc2[nt]);
                }
            }
        }
#pragma unroll
        for (int nt = 0; nt < 4; ++nt) {
            const int col = nt * 16 + lr;
#pragma unroll
            for (int r = 0; r < 4; ++r) {
                const int row = w * 16 + kg * 4 + r;
                float v = fmaxf(acc2[nt][r] + bias2[nt], 0.0f);
                sH2[row * 72 + col] = f2bf(v);
            }
        }
        __syncthreads();

        // ---- layer 3: H2 x W3t ----
        f32x4 acc3[8];
#pragma unroll
        for (int nt = 0; nt < 8; ++nt) acc3[nt] = f32x4{0.f, 0.f, 0.f, 0.f};
        {
            const int ao = (w * 16 + lr) * 72 + kg * 8;
            const int bo = lr * 72 + kg * 8;
#pragma unroll
            for (int kc = 0; kc < 2; ++kc) {
                s16x8 af = *(const s16x8*)&sH2[ao + kc * 32];
#pragma unroll
                for (int nt = 0; nt < 8; ++nt) {
                    s16x8 bf = *(const s16x8*)&W3t[bo + nt * 1152 + kc * 32];
                    acc3[nt] = mfma16(af, bf, acc3[nt]);
                }
            }
        }

        // ---- masked max (bias after max: column-constant) ----
        float pm[8];
#pragma unroll
        for (int nt = 0; nt < 8; ++nt) pm[nt] = -1e30f;
#pragma unroll
        for (int r = 0; r < 4; ++r) {
            const int row = w * 16 + kg * 4 + r;
            if (row < cnt) {
#pragma unroll
                for (int nt = 0; nt < 8; ++nt) pm[nt] = fmaxf(pm[nt], acc3[nt][r]);
            }
        }
#pragma unroll
        for (int nt = 0; nt < 8; ++nt) {
            pm[nt] = fmaxf(pm[nt], __shfl_xor(pm[nt], 16));
            pm[nt] = fmaxf(pm[nt], __shfl_xor(pm[nt], 32));
        }
        __syncthreads();            // cd/ci dead; reuse as f32 partial [4][128]
        float* pbuf = cd;
        if (kg == 0) {
#pragma unroll
            for (int nt = 0; nt < 8; ++nt) pbuf[w * 128 + nt * 16 + lr] = pm[nt];
        }
        __syncthreads();
        if (t < 128) {
            float m = fmaxf(fmaxf(pbuf[t], pbuf[128 + t]),
                            fmaxf(pbuf[256 + t], pbuf[384 + t]));
            out_x[(size_t)c * 128 + t] = m + b3r;
        }
        // loop-top barrier (after slot grab) orders pbuf reads vs next cd write
    }
}

__global__ __launch_bounds__(256) void fused_kernel(
    const float* __restrict__ pos, const float* __restrict__ x,
    const unsigned short* __restrict__ wsW,
    const float* __restrict__ b1, const float* __restrict__ b2,
    const float* __restrict__ b3,
    int* __restrict__ sel, int* __restrict__ prog, int* __restrict__ wq,
    float* __restrict__ out_x, float* __restrict__ out_pos,
    float* __restrict__ out_batch)
{
    extern __shared__ char smem[];
    if (blockIdx.x < NB) {
        fps_body(smem, pos, sel, prog);
        __syncthreads();            // then join the worker pool (CU was idle)
    }
    worker_loop(smem, pos, x, wsW, b1, b2, b3, sel, prog, wq,
                out_x, out_pos, out_batch);
}

extern "C" void kernel_launch(void* const* d_in, const int* in_sizes, int n_in,
                              void* d_out, int out_size, void* d_ws, size_t ws_size,
                              hipStream_t stream)
{
    const float* x   = (const float*)d_in[0];
    const float* pos = (const float*)d_in[1];
    const float* W1 = (const float*)d_in[3];
    const float* b1 = (const float*)d_in[4];
    const float* W2 = (const float*)d_in[5];
    const float* b2 = (const float*)d_in[6];
    const float* W3 = (const float*)d_in[7];
    const float* b3 = (const float*)d_in[8];

    float* out_x     = (float*)d_out;                    // [8192,128]
    float* out_pos   = out_x + (size_t)MTOT * 128;       // [8192,3]
    float* out_batch = out_pos + (size_t)MTOT * 3;       // [8192]

    int* sel  = (int*)d_ws;                              // [8192]
    int* prog = sel + MTOT;                              // [128] (8 used, stride 16)
    int* wq   = prog + 128;                              // [16]  (1 used)
    unsigned short* wsW = (unsigned short*)(wq + 16);    // [20480] bf16 weights

    (void)hipFuncSetAttribute((const void*)fused_kernel,
                              hipFuncAttributeMaxDynamicSharedMemorySize, 86016);

    prep_weights<<<(WTOT_U + 255) / 256, 256, 0, stream>>>(W1, W2, W3, wsW);
    init_sync<<<1, 64, 0, stream>>>(prog, wq);
    fused_kernel<<<256, 256, 86016, stream>>>(pos, x, wsW, b1, b2, b3,
                                              sel, prog, wq,
                                              out_x, out_pos, out_batch);
}

// Round 11
// 703.878 us; speedup vs baseline: 1.1757x; 1.0134x over previous
//
#include <hip/hip_runtime.h>
#include <math.h>

#define NB   8
#define NPTS 4096
#define MPER 1024
#define MTOT (NB*MPER)
#define CIN  64
#define KNN  64
#define PUB  32
// (0.2*0.2) computed in double, as the reference's python-float R*R
#define R2D  0.04000000000000001

typedef unsigned int u32;
typedef unsigned long long u64;
typedef float v2f __attribute__((ext_vector_type(2)));
using s16x8 = __attribute__((ext_vector_type(8))) short;   // 8 bf16 (4 VGPRs)
using f32x4 = __attribute__((ext_vector_type(4))) float;

// exact IEEE fp32 distance, reference order: ((dx*dx + dy*dy) + dz*dz), no FMA
__device__ __forceinline__ float d2f(float ax, float ay, float az,
                                     float bx, float by, float bz) {
    float dx = __fsub_rn(ax, bx);
    float dy = __fsub_rn(ay, by);
    float dz = __fsub_rn(az, bz);
    return __fadd_rn(__fadd_rn(__fmul_rn(dx, dx), __fmul_rn(dy, dy)),
                     __fmul_rn(dz, dz));
}

// CDNA packed 2xFP32 ops — IEEE-identical per component; asm, never contracted.
__device__ __forceinline__ v2f pk_add(v2f a, v2f b) {
    v2f d;
    asm("v_pk_add_f32 %0, %1, %2" : "=v"(d) : "v"(a), "v"(b));
    return d;
}
__device__ __forceinline__ v2f pk_mul(v2f a, v2f b) {
    v2f d;
    asm("v_pk_mul_f32 %0, %1, %2" : "=v"(d) : "v"(a), "v"(b));
    return d;
}

// float -> bf16 bits, round-to-nearest-even (finite inputs only)
__device__ __forceinline__ unsigned short f2bf(float f) {
    u32 x = __float_as_uint(f);
    u32 r = (x + 0x7fffu + ((x >> 16) & 1u)) >> 16;
    return (unsigned short)r;
}
__device__ __forceinline__ u32 pk2(float a, float b) {
    return (u32)f2bf(a) | ((u32)f2bf(b) << 16);
}

__device__ __forceinline__ f32x4 mfma16(s16x8 a, s16x8 b, f32x4 c) {
    return __builtin_amdgcn_mfma_f32_16x16x32_bf16(a, b, c, 0, 0, 0);
}

// full-wave (64-lane) max reduction of a u64 key via DPP; result valid in lane 63.
__device__ __forceinline__ u64 wave_max_u64_dpp(u64 key)
{
#define DPPMAX(ctrl, rmask) do {                                                   \
        u32 lo_ = (u32)key;                                                        \
        u32 hi_ = (u32)(key >> 32);                                                \
        u32 plo = (u32)__builtin_amdgcn_update_dpp(                                \
            0, (int)lo_, ctrl, rmask, 0xf, false);                                 \
        u32 phi = (u32)__builtin_amdgcn_update_dpp(                                \
            0, (int)hi_, ctrl, rmask, 0xf, false);                                 \
        u64 pk = ((u64)phi << 32) | plo;                                           \
        if (pk > key) key = pk;                                                    \
    } while (0)
    DPPMAX(0x111, 0xf);   // row_shr:1
    DPPMAX(0x112, 0xf);   // row_shr:2
    DPPMAX(0x114, 0xf);   // row_shr:4
    DPPMAX(0x118, 0xf);   // row_shr:8
    DPPMAX(0x142, 0xa);   // row_bcast:15 -> rows 1,3
    DPPMAX(0x143, 0xc);   // row_bcast:31 -> rows 2,3
#undef DPPMAX
    return key;
}

// ---------------- weight prep + sync init (merged; block 80 = init) -----------
#define W1T_U 6656
#define W2T_U 4608
#define W3T_U 9216
#define WTOT_U 20480

__global__ __launch_bounds__(256) void prep_weights(
    const float* __restrict__ W1, const float* __restrict__ W2,
    const float* __restrict__ W3, unsigned short* __restrict__ wsW,
    int* __restrict__ prog, int* __restrict__ wq)
{
    if (blockIdx.x == 80) {
        int t = threadIdx.x;
        if (t < NB) prog[t * 16] = -1;
        if (t == NB) *wq = 0;
        return;
    }
    int i = blockIdx.x * 256 + threadIdx.x;
    float v;
    if (i < W1T_U) {
        int cr = i / 104, k = i - cr * 104;
        v = (k < 67) ? W1[k * 64 + cr] : 0.0f;
    } else if (i < W1T_U + W2T_U) {
        int j = i - W1T_U;
        int cr = j / 72, k = j - cr * 72;
        v = (k < 64) ? W2[k * 64 + cr] : 0.0f;
    } else {
        int j = i - (W1T_U + W2T_U);
        int cr = j / 72, k = j - cr * 72;
        v = (k < 64) ? W3[k * 128 + cr] : 0.0f;
    }
    wsW[i] = f2bf(v);
}

// ================= fused kernel: 8 FPS blocks + 248 persistent workers =========
// dynamic LDS = 86016 B -> exactly 1 block/CU, all 256 blocks co-resident.
// Message passing is ATOMIC-ONLY (relaxed atomics at the coherent point):
// no acquire/release -> no L2 inval/writeback storms (round-10 lesson:
// acquire-polling invalidated L2 everywhere -> 43MB HBM refetch + FPS slowdown).
// Producer orders sel-stores before prog-store with raw s_waitcnt vmcnt(0).

// ---- FPS producer (r7-proven structure; 591us standalone) ----
__device__ __forceinline__ void fps_body(char* smem, const float* __restrict__ pos,
                                         int* __restrict__ sel, int* __restrict__ prog)
{
    const int b    = blockIdx.x;
    const int t    = threadIdx.x;
    const int lane = t & 63;
    const int wv   = t >> 6;
    const float* pb = pos + (size_t)b * NPTS * 3;

    float4* lp = (float4*)smem;              // 64 KB
    u64*    part = (u64*)(smem + 65536);     // [2][4]

    v2f px[8], py[8], pz[8], mind[8];
#pragma unroll
    for (int pr = 0; pr < 8; ++pr) {
        int j0 = (2 * pr + 0) * 256 + t;
        int j1 = (2 * pr + 1) * 256 + t;
        float x0 = pb[j0 * 3 + 0], y0 = pb[j0 * 3 + 1], z0 = pb[j0 * 3 + 2];
        float x1 = pb[j1 * 3 + 0], y1 = pb[j1 * 3 + 1], z1 = pb[j1 * 3 + 2];
        px[pr] = v2f{x0, x1}; py[pr] = v2f{y0, y1}; pz[pr] = v2f{z0, z1};
        mind[pr] = v2f{3.0e38f, 3.0e38f};
        lp[j0] = float4{x0, y0, z0, 0.f};
        lp[j1] = float4{x1, y1, z1, 0.f};
    }
    if (t == 0)
        __hip_atomic_store(&sel[b * MPER + 0], b * NPTS + 0,
                           __ATOMIC_RELAXED, __HIP_MEMORY_SCOPE_AGENT);
    __syncthreads();

    float4 c0 = lp[0];
    float cx = c0.x, cy = c0.y, cz = c0.z;

    for (int it = 1; it < MPER; ++it) {
        const v2f ncx = v2f{-cx, -cx};
        const v2f ncy = v2f{-cy, -cy};
        const v2f ncz = v2f{-cz, -cz};

        float bv = -1.0f; int bi = 0;
#pragma unroll
        for (int pr = 0; pr < 8; ++pr) {
            v2f dx = pk_add(px[pr], ncx);
            v2f dy = pk_add(py[pr], ncy);
            v2f dz = pk_add(pz[pr], ncz);
            v2f s  = pk_add(pk_mul(dx, dx), pk_mul(dy, dy));
            v2f d2 = pk_add(s, pk_mul(dz, dz));
            float m0 = fminf(mind[pr].x, d2.x);
            float m1 = fminf(mind[pr].y, d2.y);
            mind[pr].x = m0; mind[pr].y = m1;
            if (m0 > bv) { bv = m0; bi = (2 * pr + 0) * 256 + t; }
            if (m1 > bv) { bv = m1; bi = (2 * pr + 1) * 256 + t; }
        }

        u64 key = ((u64)__float_as_uint(bv) << 32) | (u32)(~bi);
        key = wave_max_u64_dpp(key);

        const int p = it & 1;
        if (lane == 63) part[p * 4 + wv] = key;
        __syncthreads();

        u64 k0 = part[p * 4 + 0];
        u64 k1 = part[p * 4 + 1];
        u64 k2 = part[p * 4 + 2];
        u64 k3 = part[p * 4 + 3];
        u64 ka = k0 > k1 ? k0 : k1;
        u64 kb = k2 > k3 ? k2 : k3;
        u64 km = ka > kb ? ka : kb;
        int pick = (int)(~(u32)km);

        float4 cc = lp[pick];
        cx = cc.x; cy = cc.y; cz = cc.z;
        if (t == 0) {
            __hip_atomic_store(&sel[b * MPER + it], b * NPTS + pick,
                               __ATOMIC_RELAXED, __HIP_MEMORY_SCOPE_AGENT);
            if ((it & (PUB - 1)) == (PUB - 1)) {
                // drain sel stores to the coherent point, then publish progress
                asm volatile("s_waitcnt vmcnt(0)" ::: "memory");
                __hip_atomic_store(&prog[b * 16], it,
                                   __ATOMIC_RELAXED, __HIP_MEMORY_SCOPE_AGENT);
            }
        }
    }
}

// ---- worker: queue -> relaxed-poll publish -> ballq -> MFMA MLP -> outputs ----
__device__ __forceinline__ void worker_loop(
    char* smem, const float* __restrict__ pos, const float* __restrict__ x,
    const unsigned short* __restrict__ wsW,
    const float* __restrict__ b1, const float* __restrict__ b2,
    const float* __restrict__ b3,
    int* __restrict__ sel, int* __restrict__ prog, int* __restrict__ wq,
    float* __restrict__ out_x, float* __restrict__ out_pos,
    float* __restrict__ out_batch)
{
    const int t = threadIdx.x;
    const int l = t & 63, w = t >> 6, lr = l & 15, kg = l >> 4;

    unsigned short* sW   = (unsigned short*)smem;              // 40960 B
    unsigned short* sA1  = (unsigned short*)(smem + 40960);    // [64][104]
    unsigned short* sH1  = (unsigned short*)(smem + 54272);    // [64][72]
    unsigned short* sH2  = (unsigned short*)(smem + 63488);    // [64][72]
    float* cd   = (float*)(smem + 72704);                      // [4][128]
    int*   ci   = (int*)(smem + 74752);                        // [4][128]
    int*   nbrl = (int*)(smem + 76800);                        // [64]
    int*   scnt = (int*)(smem + 77056);                        // [4]
    float* sq   = (float*)(smem + 77072);                      // [3]
    int*   sslot= (int*)(smem + 77084);                        // [1]

    // stage weights once (persist across centroids)
    {
        const uint4* src = (const uint4*)wsW;
        uint4* dst = (uint4*)sW;
#pragma unroll
        for (int i = 0; i < 10; ++i) dst[t + 256 * i] = src[t + 256 * i];
    }
    float bias1[4], bias2[4];
#pragma unroll
    for (int nt = 0; nt < 4; ++nt) {
        bias1[nt] = b1[nt * 16 + lr];
        bias2[nt] = b2[nt * 16 + lr];
    }
    const float b3r = (t < 128) ? b3[t] : 0.0f;

    const unsigned short* W1t = sW;                 // stride 104
    const unsigned short* W2t = sW + W1T_U;         // stride 72
    const unsigned short* W3t = sW + W1T_U + W2T_U; // stride 72

    for (;;) {
        if (t == 0) {
            int s = __hip_atomic_fetch_add(wq, 1, __ATOMIC_RELAXED,
                                           __HIP_MEMORY_SCOPE_AGENT);
            sslot[0] = s;
            if (s < MTOT) {
                const int it = s >> 3, b = s & 7;
                const int c = b * MPER + it;
                int p_;
                do {
                    p_ = __hip_atomic_load(&prog[b * 16], __ATOMIC_RELAXED,
                                           __HIP_MEMORY_SCOPE_AGENT);
                    if (p_ < it) __builtin_amdgcn_s_sleep(32);
                } while (p_ < it);
                int sg = __hip_atomic_load(&sel[c], __ATOMIC_RELAXED,
                                           __HIP_MEMORY_SCOPE_AGENT);
                float qx = pos[(size_t)sg * 3 + 0];
                float qy = pos[(size_t)sg * 3 + 1];
                float qz = pos[(size_t)sg * 3 + 2];
                sq[0] = qx; sq[1] = qy; sq[2] = qz;
                out_pos[(size_t)c * 3 + 0] = qx;
                out_pos[(size_t)c * 3 + 1] = qy;
                out_pos[(size_t)c * 3 + 2] = qz;
                out_batch[c] = (float)b;
            }
        }
        __syncthreads();
        const int s = sslot[0];
        if (s >= MTOT) break;                        // block-uniform exit
        const int it = s >> 3, b = s & 7;
        const int c = b * MPER + it;
        const float qx = sq[0], qy = sq[1], qz = sq[2];

        // ---- ballq: wave w scans quarter [w*1024,(w+1)*1024); rank select is
        // order-independent, so the 4-way segmented compaction preserves output
        const float* pb2 = pos + (size_t)b * NPTS * 3;
        int nw = 0;
        for (int r0 = 0; r0 < 1024; r0 += 64) {
            int j = w * 1024 + r0 + l;
            float xx = pb2[j * 3 + 0], yy = pb2[j * 3 + 1], zz = pb2[j * 3 + 2];
            float d2 = d2f(xx, yy, zz, qx, qy, qz);
            bool inside = ((double)d2 <= R2D);
            u64 m = __ballot(inside);
            if (inside) {
                int off = nw + __popcll(m & ((1ull << l) - 1ull));
                if (off < 128) { cd[w * 128 + off] = d2; ci[w * 128 + off] = j; }
            }
            nw += __popcll(m);
        }
        nw = min(nw, 128);
        if (l == 0) scnt[w] = nw;
        __syncthreads();
        const int n0 = scnt[0], n1 = scnt[1], n2 = scnt[2], n3 = scnt[3];
        const int ntot = n0 + n1 + n2 + n3;
        const int cnt = min(ntot, KNN);

        for (int f = t; f < ntot; f += 256) {
            int w2, i2;
            if (f < n0)                { w2 = 0; i2 = f; }
            else if (f < n0 + n1)      { w2 = 1; i2 = f - n0; }
            else if (f < n0 + n1 + n2) { w2 = 2; i2 = f - n0 - n1; }
            else                       { w2 = 3; i2 = f - n0 - n1 - n2; }
            float d = cd[w2 * 128 + i2]; int id = ci[w2 * 128 + i2];
            int rank = 0;
#pragma unroll
            for (int w3 = 0; w3 < 4; ++w3) {
                int nn = scnt[w3];
                for (int j = 0; j < nn; ++j) {
                    float dj = cd[w3 * 128 + j]; int ij = ci[w3 * 128 + j];
                    rank += (dj < d || (dj == d && ij < id)) ? 1 : 0;
                }
            }
            if (rank < KNN) nbrl[rank] = id;
        }
        __syncthreads();

        // ---- A1 staging: row k = [bf16(x[nb]), bf16(pos[nb]-q), zeros] ----
        {
            const int k = t >> 2, g = t & 3;
            const bool valid = k < cnt;
            const int nbg = valid ? (b * NPTS + nbrl[k]) : 0;
            const float* xr = x + (size_t)nbg * CIN + g * 16;
            float4 f0, f1, f2, f3;
            if (valid) {
                f0 = *(const float4*)(xr + 0);
                f1 = *(const float4*)(xr + 4);
                f2 = *(const float4*)(xr + 8);
                f3 = *(const float4*)(xr + 12);
            } else {
                f0 = float4{0.f, 0.f, 0.f, 0.f};
                f1 = f0; f2 = f0; f3 = f0;
            }
            uint4 ua = { pk2(f0.x, f0.y), pk2(f0.z, f0.w), pk2(f1.x, f1.y), pk2(f1.z, f1.w) };
            uint4 ub = { pk2(f2.x, f2.y), pk2(f2.z, f2.w), pk2(f3.x, f3.y), pk2(f3.z, f3.w) };
            *(uint4*)&sA1[k * 104 + g * 16 + 0] = ua;
            *(uint4*)&sA1[k * 104 + g * 16 + 8] = ub;
            if (g == 0) {
                float r0 = 0.f, r1 = 0.f, r2 = 0.f;
                if (valid) {
                    r0 = __fsub_rn(pos[(size_t)nbg * 3 + 0], qx);
                    r1 = __fsub_rn(pos[(size_t)nbg * 3 + 1], qy);
                    r2 = __fsub_rn(pos[(size_t)nbg * 3 + 2], qz);
                }
                uint4 uz = { 0u, 0u, 0u, 0u };
                uint4 ur = { pk2(r0, r1), (u32)f2bf(r2), 0u, 0u };
                *(uint4*)&sA1[k * 104 + 64] = ur;
                *(uint4*)&sA1[k * 104 + 72] = uz;
                *(uint4*)&sA1[k * 104 + 80] = uz;
                *(uint4*)&sA1[k * 104 + 88] = uz;
                *(uint4*)&sA1[k * 104 + 96] = uz;
            }
        }
        __syncthreads();

        // ---- layer 1: A1 x W1t -> H1 (relu) ----
        f32x4 acc1[4];
#pragma unroll
        for (int nt = 0; nt < 4; ++nt) acc1[nt] = f32x4{0.f, 0.f, 0.f, 0.f};
        {
            const int ao = (w * 16 + lr) * 104 + kg * 8;
            const int bo = lr * 104 + kg * 8;
#pragma unroll
            for (int kc = 0; kc < 3; ++kc) {
                s16x8 af = *(const s16x8*)&sA1[ao + kc * 32];
#pragma unroll
                for (int nt = 0; nt < 4; ++nt) {
                    s16x8 bf = *(const s16x8*)&W1t[bo + nt * 1664 + kc * 32];
                    acc1[nt] = mfma16(af, bf, acc1[nt]);
                }
            }
        }
#pragma unroll
        for (int nt = 0; nt < 4; ++nt) {
            const int col = nt * 16 + lr;
#pragma unroll
            for (int r = 0; r < 4; ++r) {
                const int row = w * 16 + kg * 4 + r;
                float v = fmaxf(acc1[nt][r] + bias1[nt], 0.0f);
                sH1[row * 72 + col] = f2bf(v);
            }
        }
        __syncthreads();

        // ---- layer 2: H1 x W2t -> H2 (relu) ----
        f32x4 acc2[4];
#pragma unroll
        for (int nt = 0; nt < 4; ++nt) acc2[nt] = f32x4{0.f, 0.f, 0.f, 0.f};
        {
            const int ao = (w * 16 + lr) * 72 + kg * 8;
            const int bo = lr * 72 + kg * 8;
#pragma unroll
            for (int kc = 0; kc < 2; ++kc) {
                s16x8 af = *(const s16x8*)&sH1[ao + kc * 32];
#pragma unroll
                for (int nt = 0; nt < 4; ++nt) {
                    s16x8 bf = *(const s16x8*)&W2t[bo + nt * 1152 + kc * 32];
                    acc2[nt] = mfma16(af, bf, acc2[nt]);
                }
            }
        }
#pragma unroll
        for (int nt = 0; nt < 4; ++nt) {
            const int col = nt * 16 + lr;
#pragma unroll
            for (int r = 0; r < 4; ++r) {
                const int row = w * 16 + kg * 4 + r;
                float v = fmaxf(acc2[nt][r] + bias2[nt], 0.0f);
                sH2[row * 72 + col] = f2bf(v);
            }
        }
        __syncthreads();

        // ---- layer 3: H2 x W3t ----
        f32x4 acc3[8];
#pragma unroll
        for (int nt = 0; nt < 8; ++nt) acc3[nt] = f32x4{0.f, 0.f, 0.f, 0.f};
        {
            const int ao = (w * 16 + lr) * 72 + kg * 8;
            const int bo = lr * 72 + kg * 8;
#pragma unroll
            for (int kc = 0; kc < 2; ++kc) {
                s16x8 af = *(const s16x8*)&sH2[ao + kc * 32];
#pragma unroll
                for (int nt = 0; nt < 8; ++nt) {
                    s16x8 bf = *(const s16x8*)&W3t[bo + nt * 1152 + kc * 32];
                    acc3[nt] = mfma16(af, bf, acc3[nt]);
                }
            }
        }

        // ---- masked max (bias after max: column-constant) ----
        float pm[8];
#pragma unroll
        for (int nt = 0; nt < 8; ++nt) pm[nt] = -1e30f;
#pragma unroll
        for (int r = 0; r < 4; ++r) {
            const int row = w * 16 + kg * 4 + r;
            if (row < cnt) {
#pragma unroll
                for (int nt = 0; nt < 8; ++nt) pm[nt] = fmaxf(pm[nt], acc3[nt][r]);
            }
        }
#pragma unroll
        for (int nt = 0; nt < 8; ++nt) {
            pm[nt] = fmaxf(pm[nt], __shfl_xor(pm[nt], 16));
            pm[nt] = fmaxf(pm[nt], __shfl_xor(pm[nt], 32));
        }
        __syncthreads();            // cd/ci dead; reuse as f32 partial [4][128]
        float* pbuf = cd;
        if (kg == 0) {
#pragma unroll
            for (int nt = 0; nt < 8; ++nt) pbuf[w * 128 + nt * 16 + lr] = pm[nt];
        }
        __syncthreads();
        if (t < 128) {
            float m = fmaxf(fmaxf(pbuf[t], pbuf[128 + t]),
                            fmaxf(pbuf[256 + t], pbuf[384 + t]));
            out_x[(size_t)c * 128 + t] = m + b3r;
        }
        // loop-top barrier (after slot grab) orders pbuf reads vs next cd write
    }
}

__global__ __launch_bounds__(256) void fused_kernel(
    const float* __restrict__ pos, const float* __restrict__ x,
    const unsigned short* __restrict__ wsW,
    const float* __restrict__ b1, const float* __restrict__ b2,
    const float* __restrict__ b3,
    int* __restrict__ sel, int* __restrict__ prog, int* __restrict__ wq,
    float* __restrict__ out_x, float* __restrict__ out_pos,
    float* __restrict__ out_batch)
{
    extern __shared__ char smem[];
    if (blockIdx.x < NB) {
        fps_body(smem, pos, sel, prog);
        __syncthreads();            // then join the worker pool (CU was idle)
    }
    worker_loop(smem, pos, x, wsW, b1, b2, b3, sel, prog, wq,
                out_x, out_pos, out_batch);
}

extern "C" void kernel_launch(void* const* d_in, const int* in_sizes, int n_in,
                              void* d_out, int out_size, void* d_ws, size_t ws_size,
                              hipStream_t stream)
{
    const float* x   = (const float*)d_in[0];
    const float* pos = (const float*)d_in[1];
    const float* W1 = (const float*)d_in[3];
    const float* b1 = (const float*)d_in[4];
    const float* W2 = (const float*)d_in[5];
    const float* b2 = (const float*)d_in[6];
    const float* W3 = (const float*)d_in[7];
    const float* b3 = (const float*)d_in[8];

    float* out_x     = (float*)d_out;                    // [8192,128]
    float* out_pos   = out_x + (size_t)MTOT * 128;       // [8192,3]
    float* out_batch = out_pos + (size_t)MTOT * 3;       // [8192]

    int* sel  = (int*)d_ws;                              // [8192]
    int* prog = sel + MTOT;                              // [128] (8 used, stride 16)
    int* wq   = prog + 128;                              // [16]  (1 used)
    unsigned short* wsW = (unsigned short*)(wq + 16);    // [20480] bf16 weights

    (void)hipFuncSetAttribute((const void*)fused_kernel,
                              hipFuncAttributeMaxDynamicSharedMemorySize, 86016);

    prep_weights<<<81, 256, 0, stream>>>(W1, W2, W3, wsW, prog, wq);
    fused_kernel<<<256, 256, 86016, stream>>>(pos, x, wsW, b1, b2, b3,
                                              sel, prog, wq,
                                              out_x, out_pos, out_batch);
}

// Round 12
// 677.789 us; speedup vs baseline: 1.2209x; 1.0385x over previous
//
#include <hip/hip_runtime.h>
#include <math.h>

#define NB   8
#define NPTS 4096
#define MPER 1024
#define MTOT (NB*MPER)
#define CIN  64
#define KNN  64
// (0.2*0.2) computed in double, as the reference's python-float R*R
#define R2D  0.04000000000000001

typedef unsigned int u32;
typedef unsigned long long u64;
typedef float v2f __attribute__((ext_vector_type(2)));
using s16x8 = __attribute__((ext_vector_type(8))) short;   // 8 bf16 (4 VGPRs)
using f32x4 = __attribute__((ext_vector_type(4))) float;

// exact IEEE fp32 distance, reference order: ((dx*dx + dy*dy) + dz*dz), no FMA
__device__ __forceinline__ float d2f(float ax, float ay, float az,
                                     float bx, float by, float bz) {
    float dx = __fsub_rn(ax, bx);
    float dy = __fsub_rn(ay, by);
    float dz = __fsub_rn(az, bz);
    return __fadd_rn(__fadd_rn(__fmul_rn(dx, dx), __fmul_rn(dy, dy)),
                     __fmul_rn(dz, dz));
}

// CDNA packed 2xFP32 ops — IEEE-identical per component; asm, never contracted.
__device__ __forceinline__ v2f pk_add(v2f a, v2f b) {
    v2f d;
    asm("v_pk_add_f32 %0, %1, %2" : "=v"(d) : "v"(a), "v"(b));
    return d;
}
__device__ __forceinline__ v2f pk_mul(v2f a, v2f b) {
    v2f d;
    asm("v_pk_mul_f32 %0, %1, %2" : "=v"(d) : "v"(a), "v"(b));
    return d;
}

// float -> bf16 bits, round-to-nearest-even (finite inputs only)
__device__ __forceinline__ unsigned short f2bf(float f) {
    u32 x = __float_as_uint(f);
    u32 r = (x + 0x7fffu + ((x >> 16) & 1u)) >> 16;
    return (unsigned short)r;
}
__device__ __forceinline__ u32 pk2(float a, float b) {
    return (u32)f2bf(a) | ((u32)f2bf(b) << 16);
}

__device__ __forceinline__ f32x4 mfma16(s16x8 a, s16x8 b, f32x4 c) {
    return __builtin_amdgcn_mfma_f32_16x16x32_bf16(a, b, c, 0, 0, 0);
}

// full-wave (64-lane) max reduction of a u64 key via DPP; result valid in lane 63.
__device__ __forceinline__ u64 wave_max_u64_dpp(u64 key)
{
#define DPPMAX(ctrl, rmask) do {                                                   \
        u32 lo_ = (u32)key;                                                        \
        u32 hi_ = (u32)(key >> 32);                                                \
        u32 plo = (u32)__builtin_amdgcn_update_dpp(                                \
            0, (int)lo_, ctrl, rmask, 0xf, false);                                 \
        u32 phi = (u32)__builtin_amdgcn_update_dpp(                                \
            0, (int)hi_, ctrl, rmask, 0xf, false);                                 \
        u64 pk = ((u64)phi << 32) | plo;                                           \
        if (pk > key) key = pk;                                                    \
    } while (0)
    DPPMAX(0x111, 0xf);   // row_shr:1
    DPPMAX(0x112, 0xf);   // row_shr:2
    DPPMAX(0x114, 0xf);   // row_shr:4
    DPPMAX(0x118, 0xf);   // row_shr:8
    DPPMAX(0x142, 0xa);   // row_bcast:15 -> rows 1,3
    DPPMAX(0x143, 0xc);   // row_bcast:31 -> rows 2,3
#undef DPPMAX
    return key;
}

// ---------------- prep: bf16 weights (blk 0-79) + sel=-1 (blk 80-111) + wq ----
#define W1T_U 6656
#define W2T_U 4608
#define W3T_U 9216
#define WTOT_U 20480

__global__ __launch_bounds__(256) void prep_weights(
    const float* __restrict__ W1, const float* __restrict__ W2,
    const float* __restrict__ W3, unsigned short* __restrict__ wsW,
    int* __restrict__ sel, int* __restrict__ wq)
{
    const int bid = blockIdx.x;
    const int t = threadIdx.x;
    if (bid >= 112) {                     // wq init
        if (t == 0) *wq = 0;
        return;
    }
    if (bid >= 80) {                      // sel sentinel init (-1: unpublished)
        sel[(bid - 80) * 256 + t] = -1;
        return;
    }
    int i = bid * 256 + t;
    float v;
    if (i < W1T_U) {
        int cr = i / 104, k = i - cr * 104;
        v = (k < 67) ? W1[k * 64 + cr] : 0.0f;
    } else if (i < W1T_U + W2T_U) {
        int j = i - W1T_U;
        int cr = j / 72, k = j - cr * 72;
        v = (k < 64) ? W2[k * 64 + cr] : 0.0f;
    } else {
        int j = i - (W1T_U + W2T_U);
        int cr = j / 72, k = j - cr * 72;
        v = (k < 64) ? W3[k * 128 + cr] : 0.0f;
    }
    wsW[i] = f2bf(v);
}

// ================= fused kernel: 8 FPS blocks + 248 persistent workers =========
// dynamic LDS = 86016 B -> exactly 1 block/CU, all 256 blocks co-resident.
// Publication = the sel value itself (single word, sentinel -1) -> relaxed
// atomics only, no fences. Producer batches 8 picks in registers (lane t<8
// captures pick when it&7==t) and flushes 8 PARALLEL atomic stores every 8
// iters -> barrier vmcnt-drain pays ~1 coherent-ack per 8 iters instead of
// every iter (round-11 lesson: per-iter agent-atomic store ack stalled wave 0
// at each barrier).

// ---- FPS producer (r7-proven compute structure) ----
__device__ __forceinline__ void fps_body(char* smem, const float* __restrict__ pos,
                                         int* __restrict__ sel)
{
    const int b    = blockIdx.x;
    const int t    = threadIdx.x;
    const int lane = t & 63;
    const int wv   = t >> 6;
    const float* pb = pos + (size_t)b * NPTS * 3;

    float4* lp = (float4*)smem;              // 64 KB
    u64*    part = (u64*)(smem + 65536);     // [2][4]

    v2f px[8], py[8], pz[8], mind[8];
#pragma unroll
    for (int pr = 0; pr < 8; ++pr) {
        int j0 = (2 * pr + 0) * 256 + t;
        int j1 = (2 * pr + 1) * 256 + t;
        float x0 = pb[j0 * 3 + 0], y0 = pb[j0 * 3 + 1], z0 = pb[j0 * 3 + 2];
        float x1 = pb[j1 * 3 + 0], y1 = pb[j1 * 3 + 1], z1 = pb[j1 * 3 + 2];
        px[pr] = v2f{x0, x1}; py[pr] = v2f{y0, y1}; pz[pr] = v2f{z0, z1};
        mind[pr] = v2f{3.0e38f, 3.0e38f};
        lp[j0] = float4{x0, y0, z0, 0.f};
        lp[j1] = float4{x1, y1, z1, 0.f};
    }
    __syncthreads();

    float4 c0 = lp[0];
    float cx = c0.x, cy = c0.y, cz = c0.z;
    int mypick = 0;                          // t==0 carries slot-0 pick (idx 0)

    for (int it = 1; it < MPER; ++it) {
        const v2f ncx = v2f{-cx, -cx};
        const v2f ncy = v2f{-cy, -cy};
        const v2f ncz = v2f{-cz, -cz};

        float bv = -1.0f; int bi = 0;
#pragma unroll
        for (int pr = 0; pr < 8; ++pr) {
            v2f dx = pk_add(px[pr], ncx);
            v2f dy = pk_add(py[pr], ncy);
            v2f dz = pk_add(pz[pr], ncz);
            v2f s  = pk_add(pk_mul(dx, dx), pk_mul(dy, dy));
            v2f d2 = pk_add(s, pk_mul(dz, dz));
            float m0 = fminf(mind[pr].x, d2.x);
            float m1 = fminf(mind[pr].y, d2.y);
            mind[pr].x = m0; mind[pr].y = m1;
            if (m0 > bv) { bv = m0; bi = (2 * pr + 0) * 256 + t; }
            if (m1 > bv) { bv = m1; bi = (2 * pr + 1) * 256 + t; }
        }

        u64 key = ((u64)__float_as_uint(bv) << 32) | (u32)(~bi);
        key = wave_max_u64_dpp(key);

        const int p = it & 1;
        if (lane == 63) part[p * 4 + wv] = key;
        __syncthreads();

        u64 k0 = part[p * 4 + 0];
        u64 k1 = part[p * 4 + 1];
        u64 k2 = part[p * 4 + 2];
        u64 k3 = part[p * 4 + 3];
        u64 ka = k0 > k1 ? k0 : k1;
        u64 kb = k2 > k3 ? k2 : k3;
        u64 km = ka > kb ? ka : kb;
        int pick = (int)(~(u32)km);

        float4 cc = lp[pick];
        cx = cc.x; cy = cc.y; cz = cc.z;

        if (t < 8) {
            if ((it & 7) == t) mypick = pick;       // register capture
            if ((it & 7) == 7)                       // flush slots [it-7, it]
                __hip_atomic_store(&sel[b * MPER + (it - 7) + t],
                                   b * NPTS + mypick,
                                   __ATOMIC_RELAXED, __HIP_MEMORY_SCOPE_AGENT);
        }
    }
}

// ---- worker: queue -> sentinel-poll sel[c] -> ballq -> MFMA MLP -> outputs ----
__device__ __forceinline__ void worker_loop(
    char* smem, const float* __restrict__ pos, const float* __restrict__ x,
    const unsigned short* __restrict__ wsW,
    const float* __restrict__ b1, const float* __restrict__ b2,
    const float* __restrict__ b3,
    int* __restrict__ sel, int* __restrict__ wq,
    float* __restrict__ out_x, float* __restrict__ out_pos,
    float* __restrict__ out_batch)
{
    const int t = threadIdx.x;
    const int l = t & 63, w = t >> 6, lr = l & 15, kg = l >> 4;

    unsigned short* sW   = (unsigned short*)smem;              // 40960 B
    unsigned short* sA1  = (unsigned short*)(smem + 40960);    // [64][104]
    unsigned short* sH1  = (unsigned short*)(smem + 54272);    // [64][72]
    unsigned short* sH2  = (unsigned short*)(smem + 63488);    // [64][72]
    float* cd   = (float*)(smem + 72704);                      // [4][128]
    int*   ci   = (int*)(smem + 74752);                        // [4][128]
    int*   nbrl = (int*)(smem + 76800);                        // [64]
    int*   scnt = (int*)(smem + 77056);                        // [4]
    float* sq   = (float*)(smem + 77072);                      // [3]
    int*   sslot= (int*)(smem + 77084);                        // [1]

    // stage weights once (persist across centroids)
    {
        const uint4* src = (const uint4*)wsW;
        uint4* dst = (uint4*)sW;
#pragma unroll
        for (int i = 0; i < 10; ++i) dst[t + 256 * i] = src[t + 256 * i];
    }
    float bias1[4], bias2[4];
#pragma unroll
    for (int nt = 0; nt < 4; ++nt) {
        bias1[nt] = b1[nt * 16 + lr];
        bias2[nt] = b2[nt * 16 + lr];
    }
    const float b3r = (t < 128) ? b3[t] : 0.0f;

    const unsigned short* W1t = sW;                 // stride 104
    const unsigned short* W2t = sW + W1T_U;         // stride 72
    const unsigned short* W3t = sW + W1T_U + W2T_U; // stride 72

    for (;;) {
        if (t == 0) {
            int s = __hip_atomic_fetch_add(wq, 1, __ATOMIC_RELAXED,
                                           __HIP_MEMORY_SCOPE_AGENT);
            sslot[0] = s;
            if (s < MTOT) {
                const int it = s >> 3, b = s & 7;
                const int c = b * MPER + it;
                int sg;
                do {
                    sg = __hip_atomic_load(&sel[c], __ATOMIC_RELAXED,
                                           __HIP_MEMORY_SCOPE_AGENT);
                    if (sg < 0) __builtin_amdgcn_s_sleep(64);
                } while (sg < 0);
                float qx = pos[(size_t)sg * 3 + 0];
                float qy = pos[(size_t)sg * 3 + 1];
                float qz = pos[(size_t)sg * 3 + 2];
                sq[0] = qx; sq[1] = qy; sq[2] = qz;
                out_pos[(size_t)c * 3 + 0] = qx;
                out_pos[(size_t)c * 3 + 1] = qy;
                out_pos[(size_t)c * 3 + 2] = qz;
                out_batch[c] = (float)b;
            }
        }
        __syncthreads();
        const int s = sslot[0];
        if (s >= MTOT) break;                        // block-uniform exit
        const int it = s >> 3, b = s & 7;
        const int c = b * MPER + it;
        const float qx = sq[0], qy = sq[1], qz = sq[2];

        // ---- ballq: wave w scans quarter [w*1024,(w+1)*1024); rank select is
        // order-independent, so the 4-way segmented compaction preserves output
        const float* pb2 = pos + (size_t)b * NPTS * 3;
        int nw = 0;
        for (int r0 = 0; r0 < 1024; r0 += 64) {
            int j = w * 1024 + r0 + l;
            float xx = pb2[j * 3 + 0], yy = pb2[j * 3 + 1], zz = pb2[j * 3 + 2];
            float d2 = d2f(xx, yy, zz, qx, qy, qz);
            bool inside = ((double)d2 <= R2D);
            u64 m = __ballot(inside);
            if (inside) {
                int off = nw + __popcll(m & ((1ull << l) - 1ull));
                if (off < 128) { cd[w * 128 + off] = d2; ci[w * 128 + off] = j; }
            }
            nw += __popcll(m);
        }
        nw = min(nw, 128);
        if (l == 0) scnt[w] = nw;
        __syncthreads();
        const int n0 = scnt[0], n1 = scnt[1], n2 = scnt[2], n3 = scnt[3];
        const int ntot = n0 + n1 + n2 + n3;
        const int cnt = min(ntot, KNN);

        for (int f = t; f < ntot; f += 256) {
            int w2, i2;
            if (f < n0)                { w2 = 0; i2 = f; }
            else if (f < n0 + n1)      { w2 = 1; i2 = f - n0; }
            else if (f < n0 + n1 + n2) { w2 = 2; i2 = f - n0 - n1; }
            else                       { w2 = 3; i2 = f - n0 - n1 - n2; }
            float d = cd[w2 * 128 + i2]; int id = ci[w2 * 128 + i2];
            int rank = 0;
#pragma unroll
            for (int w3 = 0; w3 < 4; ++w3) {
                int nn = scnt[w3];
                for (int j = 0; j < nn; ++j) {
                    float dj = cd[w3 * 128 + j]; int ij = ci[w3 * 128 + j];
                    rank += (dj < d || (dj == d && ij < id)) ? 1 : 0;
                }
            }
            if (rank < KNN) nbrl[rank] = id;
        }
        __syncthreads();

        // ---- A1 staging: row k = [bf16(x[nb]), bf16(pos[nb]-q), zeros] ----
        {
            const int k = t >> 2, g = t & 3;
            const bool valid = k < cnt;
            const int nbg = valid ? (b * NPTS + nbrl[k]) : 0;
            const float* xr = x + (size_t)nbg * CIN + g * 16;
            float4 f0, f1, f2, f3;
            if (valid) {
                f0 = *(const float4*)(xr + 0);
                f1 = *(const float4*)(xr + 4);
                f2 = *(const float4*)(xr + 8);
                f3 = *(const float4*)(xr + 12);
            } else {
                f0 = float4{0.f, 0.f, 0.f, 0.f};
                f1 = f0; f2 = f0; f3 = f0;
            }
            uint4 ua = { pk2(f0.x, f0.y), pk2(f0.z, f0.w), pk2(f1.x, f1.y), pk2(f1.z, f1.w) };
            uint4 ub = { pk2(f2.x, f2.y), pk2(f2.z, f2.w), pk2(f3.x, f3.y), pk2(f3.z, f3.w) };
            *(uint4*)&sA1[k * 104 + g * 16 + 0] = ua;
            *(uint4*)&sA1[k * 104 + g * 16 + 8] = ub;
            if (g == 0) {
                float r0 = 0.f, r1 = 0.f, r2 = 0.f;
                if (valid) {
                    r0 = __fsub_rn(pos[(size_t)nbg * 3 + 0], qx);
                    r1 = __fsub_rn(pos[(size_t)nbg * 3 + 1], qy);
                    r2 = __fsub_rn(pos[(size_t)nbg * 3 + 2], qz);
                }
                uint4 uz = { 0u, 0u, 0u, 0u };
                uint4 ur = { pk2(r0, r1), (u32)f2bf(r2), 0u, 0u };
                *(uint4*)&sA1[k * 104 + 64] = ur;
                *(uint4*)&sA1[k * 104 + 72] = uz;
                *(uint4*)&sA1[k * 104 + 80] = uz;
                *(uint4*)&sA1[k * 104 + 88] = uz;
                *(uint4*)&sA1[k * 104 + 96] = uz;
            }
        }
        __syncthreads();

        // ---- layer 1: A1 x W1t -> H1 (relu) ----
        f32x4 acc1[4];
#pragma unroll
        for (int nt = 0; nt < 4; ++nt) acc1[nt] = f32x4{0.f, 0.f, 0.f, 0.f};
        {
            const int ao = (w * 16 + lr) * 104 + kg * 8;
            const int bo = lr * 104 + kg * 8;
#pragma unroll
            for (int kc = 0; kc < 3; ++kc) {
                s16x8 af = *(const s16x8*)&sA1[ao + kc * 32];
#pragma unroll
                for (int nt = 0; nt < 4; ++nt) {
                    s16x8 bf = *(const s16x8*)&W1t[bo + nt * 1664 + kc * 32];
                    acc1[nt] = mfma16(af, bf, acc1[nt]);
                }
            }
        }
#pragma unroll
        for (int nt = 0; nt < 4; ++nt) {
            const int col = nt * 16 + lr;
#pragma unroll
            for (int r = 0; r < 4; ++r) {
                const int row = w * 16 + kg * 4 + r;
                float v = fmaxf(acc1[nt][r] + bias1[nt], 0.0f);
                sH1[row * 72 + col] = f2bf(v);
            }
        }
        __syncthreads();

        // ---- layer 2: H1 x W2t -> H2 (relu) ----
        f32x4 acc2[4];
#pragma unroll
        for (int nt = 0; nt < 4; ++nt) acc2[nt] = f32x4{0.f, 0.f, 0.f, 0.f};
        {
            const int ao = (w * 16 + lr) * 72 + kg * 8;
            const int bo = lr * 72 + kg * 8;
#pragma unroll
            for (int kc = 0; kc < 2; ++kc) {
                s16x8 af = *(const s16x8*)&sH1[ao + kc * 32];
#pragma unroll
                for (int nt = 0; nt < 4; ++nt) {
                    s16x8 bf = *(const s16x8*)&W2t[bo + nt * 1152 + kc * 32];
                    acc2[nt] = mfma16(af, bf, acc2[nt]);
                }
            }
        }
#pragma unroll
        for (int nt = 0; nt < 4; ++nt) {
            const int col = nt * 16 + lr;
#pragma unroll
            for (int r = 0; r < 4; ++r) {
                const int row = w * 16 + kg * 4 + r;
                float v = fmaxf(acc2[nt][r] + bias2[nt], 0.0f);
                sH2[row * 72 + col] = f2bf(v);
            }
        }
        __syncthreads();

        // ---- layer 3: H2 x W3t ----
        f32x4 acc3[8];
#pragma unroll
        for (int nt = 0; nt < 8; ++nt) acc3[nt] = f32x4{0.f, 0.f, 0.f, 0.f};
        {
            const int ao = (w * 16 + lr) * 72 + kg * 8;
            const int bo = lr * 72 + kg * 8;
#pragma unroll
            for (int kc = 0; kc < 2; ++kc) {
                s16x8 af = *(const s16x8*)&sH2[ao + kc * 32];
#pragma unroll
                for (int nt = 0; nt < 8; ++nt) {
                    s16x8 bf = *(const s16x8*)&W3t[bo + nt * 1152 + kc * 32];
                    acc3[nt] = mfma16(af, bf, acc3[nt]);
                }
            }
        }

        // ---- masked max (bias after max: column-constant) ----
        float pm[8];
#pragma unroll
        for (int nt = 0; nt < 8; ++nt) pm[nt] = -1e30f;
#pragma unroll
        for (int r = 0; r < 4; ++r) {
            const int row = w * 16 + kg * 4 + r;
            if (row < cnt) {
#pragma unroll
                for (int nt = 0; nt < 8; ++nt) pm[nt] = fmaxf(pm[nt], acc3[nt][r]);
            }
        }
#pragma unroll
        for (int nt = 0; nt < 8; ++nt) {
            pm[nt] = fmaxf(pm[nt], __shfl_xor(pm[nt], 16));
            pm[nt] = fmaxf(pm[nt], __shfl_xor(pm[nt], 32));
        }
        __syncthreads();            // cd/ci dead; reuse as f32 partial [4][128]
        float* pbuf = cd;
        if (kg == 0) {
#pragma unroll
            for (int nt = 0; nt < 8; ++nt) pbuf[w * 128 + nt * 16 + lr] = pm[nt];
        }
        __syncthreads();
        if (t < 128) {
            float m = fmaxf(fmaxf(pbuf[t], pbuf[128 + t]),
                            fmaxf(pbuf[256 + t], pbuf[384 + t]));
            out_x[(size_t)c * 128 + t] = m + b3r;
        }
        // loop-top barrier (after slot grab) orders pbuf reads vs next cd write
    }
}

__global__ __launch_bounds__(256) void fused_kernel(
    const float* __restrict__ pos, const float* __restrict__ x,
    const unsigned short* __restrict__ wsW,
    const float* __restrict__ b1, const float* __restrict__ b2,
    const float* __restrict__ b3,
    int* __restrict__ sel, int* __restrict__ wq,
    float* __restrict__ out_x, float* __restrict__ out_pos,
    float* __restrict__ out_batch)
{
    extern __shared__ char smem[];
    if (blockIdx.x < NB) {
        fps_body(smem, pos, sel);
        __syncthreads();            // then join the worker pool (CU was idle)
    }
    worker_loop(smem, pos, x, wsW, b1, b2, b3, sel, wq,
                out_x, out_pos, out_batch);
}

extern "C" void kernel_launch(void* const* d_in, const int* in_sizes, int n_in,
                              void* d_out, int out_size, void* d_ws, size_t ws_size,
                              hipStream_t stream)
{
    const float* x   = (const float*)d_in[0];
    const float* pos = (const float*)d_in[1];
    const float* W1 = (const float*)d_in[3];
    const float* b1 = (const float*)d_in[4];
    const float* W2 = (const float*)d_in[5];
    const float* b2 = (const float*)d_in[6];
    const float* W3 = (const float*)d_in[7];
    const float* b3 = (const float*)d_in[8];

    float* out_x     = (float*)d_out;                    // [8192,128]
    float* out_pos   = out_x + (size_t)MTOT * 128;       // [8192,3]
    float* out_batch = out_pos + (size_t)MTOT * 3;       // [8192]

    int* sel = (int*)d_ws;                               // [8192], -1 = unpublished
    int* wq  = sel + MTOT;                               // [16] (1 used)
    unsigned short* wsW = (unsigned short*)(wq + 16);    // [20480] bf16 weights

    (void)hipFuncSetAttribute((const void*)fused_kernel,
                              hipFuncAttributeMaxDynamicSharedMemorySize, 86016);

    prep_weights<<<113, 256, 0, stream>>>(W1, W2, W3, wsW, sel, wq);
    fused_kernel<<<256, 256, 86016, stream>>>(pos, x, wsW, b1, b2, b3,
                                              sel, wq,
                                              out_x, out_pos, out_batch);
}